// Round 19
// baseline (263.009 us; speedup 1.0000x reference)
//
#include <hip/hip_runtime.h>
#include <hip/hip_bf16.h>
#include <math.h>

// x[32,512,64,64] f32; w1[32,512] f32; w2[512,32] f32.
// Bit-replication of the numpy-fp32 reference pipeline (round-4 PASSED, absmax 0.0):
//   y = np.mean(x,(2,3))             -> numpy pairwise_sum (128-blocks, 8 accums, tree)
//   h = relu(np.einsum('bc,rc->br')) -> SSE sum-of-products (mod-4 lanes, (L0+L1)+(L2+L3))
//   s = 1/(1+np.exp(-z))             -> correctly-rounded fp32 exp via fp64, fp32 add/div
//   idx = argsort(-s, stable)[:, :256]; out = take_along_axis(x, idx)
// Round 19: TWO nodes. Node 1 fuses pool+se via producer/consumer flag (NO
// co-residency assumption -- unlike r14/r15): 2048 producer blocks (8 ch each,
// r8 pool body per wave) + 256 consumer blocks that spin on a device-scope
// counter until all producers released g_y. Deadlock-free for ANY dispatch
// order: 256 consumers < 1024 resident-block capacity -> producers always
// progress. Counter reset by node 2 (stream-ordered) -> replay-deterministic.
// se body = r18 minus w1-LDS staging (w1 global, r8-verified; LDS 4.2KB keeps
// pool at full occupancy). Node 2 = r18 gather (rank inversion + nt stores).

#define C1 512
#define C2 256
#define CMID 32
#define HW 4096   // 64*64
#define B 32
#define GRID_POOL 2048
#define GRID_SE   256

typedef float f32x4 __attribute__((ext_vector_type(4)));

__device__ float g_y[B * C1];      // pooled means, fp32 (numpy-bit-exact)
__device__ int   g_rank[B * C1];   // per-channel rank (accumulated via atomicAdd)
__device__ unsigned g_pool_done = 0;  // producer count; reset by gather node

// ---------------- Node 1: pool (producers) + SE MLP/partial-rank (consumers) --------
__global__ __launch_bounds__(512, 8) void pool_se_kernel(const float* __restrict__ x,
                                                         const float* __restrict__ w1,
                                                         const float* __restrict__ w2) {
    __shared__ float ys[C1];
    __shared__ float hs[CMID];
    __shared__ float ss[C1];      // 4.2 KB total -> pool occupancy unaffected
    int t = threadIdx.x;          // 0..511

    if (blockIdx.x < GRID_POOL) {
        // ---------- producer: 8 channels, one per wave (r8 body verbatim) ----------
        if (blockIdx.x < 32) g_rank[blockIdx.x * 512 + t] = 0;   // replay-safe zero

        int wv = t >> 6;          // wave 0..7
        int L  = t & 63;
        int bc = blockIdx.x * 8 + wv;                   // channel 0..16383
        const float* a = x + (size_t)bc * HW;
        const float* base = a + (L >> 1) * 128 + (L & 1) * 4;
        f32x4 r = *(const f32x4*)base;
#pragma unroll
        for (int i = 1; i < 16; ++i) {
            f32x4 v = *(const f32x4*)(base + 8 * i);
            r.x = __fadd_rn(r.x, v.x);
            r.y = __fadd_rn(r.y, v.y);
            r.z = __fadd_rn(r.z, v.z);
            r.w = __fadd_rn(r.w, v.w);
        }
        float s = __fadd_rn(__fadd_rn(r.x, r.y), __fadd_rn(r.z, r.w));
        s = __fadd_rn(s, __shfl_xor(s, 1));    // lane0 chain + lane1 chain
        s = __fadd_rn(s, __shfl_xor(s, 2));    // perfect tree over the 32 blocks
        s = __fadd_rn(s, __shfl_xor(s, 4));
        s = __fadd_rn(s, __shfl_xor(s, 8));
        s = __fadd_rn(s, __shfl_xor(s, 16));
        s = __fadd_rn(s, __shfl_xor(s, 32));
        if (L == 0) g_y[bc] = __fdiv_rn(s, 4096.0f);

        __syncthreads();
        if (t == 0) {
            __threadfence();   // make g_y (and g_rank zeroing) device-visible
            __hip_atomic_fetch_add(&g_pool_done, 1, __ATOMIC_ACQ_REL,
                                   __HIP_MEMORY_SCOPE_AGENT);
        }
    } else {
        // ---------- consumer: SE MLP + partial rank for (batch b, chunk j) ----------
        int sb = blockIdx.x - GRID_POOL;   // 0..255
        int b = sb >> 3;                   // batch 0..31
        int j = sb & 7;                    // candidate chunk 0..7

        // w2 row into registers BEFORE the wait (overlaps producer phase)
        f32x4 w2r[8];
#pragma unroll
        for (int i = 0; i < 8; ++i)
            w2r[i] = ((const f32x4*)(w2 + t * CMID))[i];

        if (t == 0) {
            while (__hip_atomic_load(&g_pool_done, __ATOMIC_ACQUIRE,
                                     __HIP_MEMORY_SCOPE_AGENT) < GRID_POOL)
                __builtin_amdgcn_s_sleep(2);
            // acquire at agent scope invalidates this CU's L1 -> fresh g_y below
        }
        __syncthreads();

        ys[t] = g_y[b * C1 + t];
        __syncthreads();

        // Layer 1: 32 rows x 4 independent SSE chains (numpy L0..L3), w1 from
        // global (r8-verified path; L2-cached across 256 blocks).
        if (t < CMID * 4) {
            int row = t >> 2, k = t & 3;
            const float* v = w1 + row * C1;
            float Lk = 0.f;
#pragma unroll
            for (int c = 0; c < C1; c += 8) {
                Lk = __fadd_rn(Lk, __fmul_rn(ys[c + k],     v[c + k]));
                Lk = __fadd_rn(Lk, __fmul_rn(ys[c + 4 + k], v[c + 4 + k]));
            }
            Lk = __fadd_rn(Lk, __shfl_xor(Lk, 1));   // (L0+L1),(L2+L3)
            Lk = __fadd_rn(Lk, __shfl_xor(Lk, 2));
            if (k == 0) hs[row] = Lk > 0.0f ? Lk : 0.0f;   // np.maximum(z, 0)
        }
        __syncthreads();

        // Layer 2: numpy SSE dot over CMID=32 (registers + LDS hs), then sigmoid
        {
            float L0 = 0.f, L1 = 0.f, L2 = 0.f, L3 = 0.f;
#pragma unroll
            for (int i = 0; i < 8; i += 2) {
                L0 = __fadd_rn(L0, __fmul_rn(hs[i * 4 + 0], w2r[i].x));
                L1 = __fadd_rn(L1, __fmul_rn(hs[i * 4 + 1], w2r[i].y));
                L2 = __fadd_rn(L2, __fmul_rn(hs[i * 4 + 2], w2r[i].z));
                L3 = __fadd_rn(L3, __fmul_rn(hs[i * 4 + 3], w2r[i].w));
                L0 = __fadd_rn(L0, __fmul_rn(hs[i * 4 + 4], w2r[i + 1].x));
                L1 = __fadd_rn(L1, __fmul_rn(hs[i * 4 + 5], w2r[i + 1].y));
                L2 = __fadd_rn(L2, __fmul_rn(hs[i * 4 + 6], w2r[i + 1].z));
                L3 = __fadd_rn(L3, __fmul_rn(hs[i * 4 + 7], w2r[i + 1].w));
            }
            float z = __fadd_rn(__fadd_rn(L0, L1), __fadd_rn(L2, L3));
            float e = (float)exp((double)(-z));      // correctly-rounded fp32 exp
            ss[t] = __fdiv_rn(1.0f, __fadd_rn(1.0f, e));
        }
        __syncthreads();

        // Partial stable-descending rank over candidate chunk [j*64, j*64+64):
        {
            float sc = ss[t];
            int c0 = j * 64;
            int rank = 0;
#pragma unroll 16
            for (int c = c0; c < c0 + 64; ++c) {
                float v = ss[c];
                rank += (int)((v > sc) || (v == sc && c < t));
            }
            atomicAdd(&g_rank[b * C1 + t], rank);   // int sum: order-independent
        }
    }
}

// ---------------- Node 2: gather with in-block rank inversion (r18 verbatim) --------
__global__ __launch_bounds__(512) void gather_kernel(const float* __restrict__ x,
                                                     float* __restrict__ out) {
    int bid = blockIdx.x;                      // plane 0..1023 (b*C2 + r)
    int b = bid >> 8;
    int r = bid & 255;
    int t = threadIdx.x;
    if (bid == 0 && t == 0)                    // reset for next replay (stream-ordered)
        __hip_atomic_store(&g_pool_done, 0, __ATOMIC_RELAXED, __HIP_MEMORY_SCOPE_AGENT);
    __shared__ int win;
    int rk = g_rank[b * C1 + t];
    if (rk == r) win = t;                      // exactly one match (ranks = perm)
    __syncthreads();
    int c = win;
    const f32x4* src = (const f32x4*)(x + ((size_t)(b * C1 + c)) * HW);
    f32x4* dst = (f32x4*)(out + (size_t)bid * HW);
    f32x4 v0 = src[t];
    f32x4 v1 = src[t + 512];
    __builtin_nontemporal_store(v0, &dst[t]);
    __builtin_nontemporal_store(v1, &dst[t + 512]);
}

extern "C" void kernel_launch(void* const* d_in, const int* in_sizes, int n_in,
                              void* d_out, int out_size, void* d_ws, size_t ws_size,
                              hipStream_t stream) {
    const float* x  = (const float*)d_in[0];
    const float* w1 = (const float*)d_in[1];
    const float* w2 = (const float*)d_in[2];
    float* out = (float*)d_out;

    pool_se_kernel<<<GRID_POOL + GRID_SE, 512, 0, stream>>>(x, w1, w2);
    gather_kernel<<<B * C2, 512, 0, stream>>>(x, out);
}

// Round 20
// 99.925 us; speedup vs baseline: 2.6321x; 2.6321x over previous
//
#include <hip/hip_runtime.h>
#include <hip/hip_bf16.h>
#include <math.h>

// x[32,512,64,64] f32; w1[32,512] f32; w2[512,32] f32.
// Bit-replication of the numpy-fp32 reference pipeline (round-4 PASSED, absmax 0.0):
//   y = np.mean(x,(2,3))             -> numpy pairwise_sum (128-blocks, 8 accums, tree)
//   h = relu(np.einsum('bc,rc->br')) -> SSE sum-of-products (mod-4 lanes, (L0+L1)+(L2+L3))
//   s = 1/(1+np.exp(-z))             -> correctly-rounded fp32 exp via fp64, fp32 add/div
//   idx = argsort(-s, stable)[:, :256]; out = take_along_axis(x, idx)
// Round 20: REVERT to the verified r18 3-node structure (90.4us; pool & gather
// measured AT their HBM floors, se parallelized 8x via atomic partial-rank).
// r19's producer/consumer fusion failed: launch_bounds(512,8) capped VGPR at 32
// -> pool load chain serialized (350us, 0.39TB/s). One safe change vs r18:
// se_rank layer-1 reads w1 from GLOBAL (r17-hardware-verified bit-exact path;
// r12 proved LDS staging perf-neutral) -> drops 66KB LDS + 16KB/block staging.

#define C1 512
#define C2 256
#define CMID 32
#define HW 4096   // 64*64
#define B 32

typedef float f32x4 __attribute__((ext_vector_type(4)));

__device__ float g_y[B * C1];      // pooled means, fp32 (numpy-bit-exact)
__device__ int   g_rank[B * C1];   // per-channel rank (accumulated via atomicAdd)

// ---------------- Kernel 1: numpy-pairwise mean + g_rank zeroing ----------------
// Verified r8 body (bit-exact, at HBM floor: 38.0us marginal, round-11 probe).
__global__ __launch_bounds__(256) void pool_np_kernel(const float* __restrict__ x) {
    if (blockIdx.x < 64) g_rank[blockIdx.x * 256 + threadIdx.x] = 0;

    int bc = blockIdx.x * 4 + (threadIdx.x >> 6);   // channel 0..16383
    int L = threadIdx.x & 63;
    const float* a = x + (size_t)bc * HW;
    const float* base = a + (L >> 1) * 128 + (L & 1) * 4;
    f32x4 r = *(const f32x4*)base;
#pragma unroll
    for (int i = 1; i < 16; ++i) {
        f32x4 v = *(const f32x4*)(base + 8 * i);
        r.x = __fadd_rn(r.x, v.x);
        r.y = __fadd_rn(r.y, v.y);
        r.z = __fadd_rn(r.z, v.z);
        r.w = __fadd_rn(r.w, v.w);
    }
    float s = __fadd_rn(__fadd_rn(r.x, r.y), __fadd_rn(r.z, r.w));
    s = __fadd_rn(s, __shfl_xor(s, 1));    // lane0 chain + lane1 chain
    s = __fadd_rn(s, __shfl_xor(s, 2));    // perfect tree over the 32 blocks
    s = __fadd_rn(s, __shfl_xor(s, 4));
    s = __fadd_rn(s, __shfl_xor(s, 8));
    s = __fadd_rn(s, __shfl_xor(s, 16));
    s = __fadd_rn(s, __shfl_xor(s, 32));
    if (L == 0) g_y[bc] = __fdiv_rn(s, 4096.0f);
}

// ---------------- Kernel 2: SE MLP (verified bits) + PARTIAL rank ----------------
// 256 blocks x 512 threads; block (b = bid>>3, j = bid&7). Every block of batch b
// recomputes ss[512] bit-identically (w1 from global -- r17-verified path);
// block j accumulates ranks over candidate chunk [j*64, j*64+64) via atomicAdd
// (int sum -> order-independent, deterministic).
__global__ __launch_bounds__(512) void se_rank_kernel(const float* __restrict__ w1,
                                                      const float* __restrict__ w2) {
    int b = blockIdx.x >> 3;
    int j = blockIdx.x & 7;
    int t = threadIdx.x;       // 0..511
    __shared__ float ys[C1];
    __shared__ float hs[CMID];
    __shared__ float ss[C1];

    f32x4 w2r[8];
#pragma unroll
    for (int i = 0; i < 8; ++i)
        w2r[i] = ((const f32x4*)(w2 + t * CMID))[i];

    ys[t] = g_y[b * C1 + t];
    __syncthreads();

    // Layer 1: 32 rows x 4 independent SSE chains (numpy L0..L3), w1 from global
    if (t < CMID * 4) {
        int row = t >> 2, k = t & 3;
        const float* v = w1 + row * C1;
        float Lk = 0.f;
#pragma unroll
        for (int c = 0; c < C1; c += 8) {
            Lk = __fadd_rn(Lk, __fmul_rn(ys[c + k],     v[c + k]));
            Lk = __fadd_rn(Lk, __fmul_rn(ys[c + 4 + k], v[c + 4 + k]));
        }
        Lk = __fadd_rn(Lk, __shfl_xor(Lk, 1));   // (L0+L1),(L2+L3)
        Lk = __fadd_rn(Lk, __shfl_xor(Lk, 2));
        if (k == 0) hs[row] = Lk > 0.0f ? Lk : 0.0f;   // np.maximum(z, 0)
    }
    __syncthreads();

    // Layer 2: numpy SSE dot over CMID=32 (registers + LDS hs), then sigmoid
    {
        float L0 = 0.f, L1 = 0.f, L2 = 0.f, L3 = 0.f;
#pragma unroll
        for (int i = 0; i < 8; i += 2) {
            L0 = __fadd_rn(L0, __fmul_rn(hs[i * 4 + 0], w2r[i].x));
            L1 = __fadd_rn(L1, __fmul_rn(hs[i * 4 + 1], w2r[i].y));
            L2 = __fadd_rn(L2, __fmul_rn(hs[i * 4 + 2], w2r[i].z));
            L3 = __fadd_rn(L3, __fmul_rn(hs[i * 4 + 3], w2r[i].w));
            L0 = __fadd_rn(L0, __fmul_rn(hs[i * 4 + 4], w2r[i + 1].x));
            L1 = __fadd_rn(L1, __fmul_rn(hs[i * 4 + 5], w2r[i + 1].y));
            L2 = __fadd_rn(L2, __fmul_rn(hs[i * 4 + 6], w2r[i + 1].z));
            L3 = __fadd_rn(L3, __fmul_rn(hs[i * 4 + 7], w2r[i + 1].w));
        }
        float z = __fadd_rn(__fadd_rn(L0, L1), __fadd_rn(L2, L3));
        float e = (float)exp((double)(-z));      // correctly-rounded fp32 exp
        ss[t] = __fdiv_rn(1.0f, __fadd_rn(1.0f, e));
    }
    __syncthreads();

    // Partial stable-descending rank over candidate chunk [j*64, j*64+64):
    {
        float sc = ss[t];
        int c0 = j * 64;
        int rank = 0;
#pragma unroll 16
        for (int c = c0; c < c0 + 64; ++c) {
            float v = ss[c];
            rank += (int)((v > sc) || (v == sc && c < t));
        }
        atomicAdd(&g_rank[b * C1 + t], rank);   // int sum: order-independent
    }
}

// ---------------- Kernel 3: gather with in-block rank inversion (r18 verbatim) ------
// At BW floor (38.7us marginal, round-9 probe).
__global__ __launch_bounds__(512) void gather_kernel(const float* __restrict__ x,
                                                     float* __restrict__ out) {
    int bid = blockIdx.x;                      // plane 0..1023 (b*C2 + r)
    int b = bid >> 8;
    int r = bid & 255;
    int t = threadIdx.x;
    __shared__ int win;
    int rk = g_rank[b * C1 + t];
    if (rk == r) win = t;                      // exactly one match (ranks = perm)
    __syncthreads();
    int c = win;
    const f32x4* src = (const f32x4*)(x + ((size_t)(b * C1 + c)) * HW);
    f32x4* dst = (f32x4*)(out + (size_t)bid * HW);
    f32x4 v0 = src[t];
    f32x4 v1 = src[t + 512];
    __builtin_nontemporal_store(v0, &dst[t]);
    __builtin_nontemporal_store(v1, &dst[t + 512]);
}

extern "C" void kernel_launch(void* const* d_in, const int* in_sizes, int n_in,
                              void* d_out, int out_size, void* d_ws, size_t ws_size,
                              hipStream_t stream) {
    const float* x  = (const float*)d_in[0];
    const float* w1 = (const float*)d_in[1];
    const float* w2 = (const float*)d_in[2];
    float* out = (float*)d_out;

    pool_np_kernel<<<B * C1 / 4, 256, 0, stream>>>(x);
    se_rank_kernel<<<B * 8, 512, 0, stream>>>(w1, w2);
    gather_kernel<<<B * C2, 512, 0, stream>>>(x, out);
}

// Round 21
// 90.465 us; speedup vs baseline: 2.9073x; 1.1046x over previous
//
#include <hip/hip_runtime.h>
#include <hip/hip_bf16.h>
#include <math.h>

// x[32,512,64,64] f32; w1[32,512] f32; w2[512,32] f32.
// Bit-replication of the numpy-fp32 reference pipeline (round-4 PASSED, absmax 0.0):
//   y = np.mean(x,(2,3))             -> numpy pairwise_sum (128-blocks, 8 accums, tree)
//   h = relu(np.einsum('bc,rc->br')) -> SSE sum-of-products (mod-4 lanes, (L0+L1)+(L2+L3))
//   s = 1/(1+np.exp(-z))             -> correctly-rounded fp32 exp via fp64, fp32 add/div
//   idx = argsort(-s, stable)[:, :256]; out = take_along_axis(x, idx)
// Round 21: PURE REVERT to the round-18 kernel (90.4us, best verified). r20
// isolated that w1 LDS staging in se_rank is load-bearing (-9.5us): layer-1's
// 64-step dependent chain must source w1 from LDS (~40cy hops), not global
// (~300cy hops). Structure: pool (at HBM floor) + se_rank 8x-parallel partial
// ranks via atomicAdd (order-independent int sum) + gather with in-block rank
// inversion (at BW floor, nt stores).

#define C1 512
#define C2 256
#define CMID 32
#define HW 4096   // 64*64
#define B 32
#define W1PAD 516  // 512 + 4-float pad

typedef float f32x4 __attribute__((ext_vector_type(4)));

__device__ float g_y[B * C1];      // pooled means, fp32 (numpy-bit-exact)
__device__ int   g_rank[B * C1];   // per-channel rank (accumulated via atomicAdd)

// ---------------- Kernel 1: numpy-pairwise mean + g_rank zeroing ----------------
// Verified r8 body (bit-exact, at HBM floor: 38.0us marginal, round-11 probe).
__global__ __launch_bounds__(256) void pool_np_kernel(const float* __restrict__ x) {
    if (blockIdx.x < 64) g_rank[blockIdx.x * 256 + threadIdx.x] = 0;

    int bc = blockIdx.x * 4 + (threadIdx.x >> 6);   // channel 0..16383
    int L = threadIdx.x & 63;
    const float* a = x + (size_t)bc * HW;
    const float* base = a + (L >> 1) * 128 + (L & 1) * 4;
    f32x4 r = *(const f32x4*)base;
#pragma unroll
    for (int i = 1; i < 16; ++i) {
        f32x4 v = *(const f32x4*)(base + 8 * i);
        r.x = __fadd_rn(r.x, v.x);
        r.y = __fadd_rn(r.y, v.y);
        r.z = __fadd_rn(r.z, v.z);
        r.w = __fadd_rn(r.w, v.w);
    }
    float s = __fadd_rn(__fadd_rn(r.x, r.y), __fadd_rn(r.z, r.w));
    s = __fadd_rn(s, __shfl_xor(s, 1));    // lane0 chain + lane1 chain
    s = __fadd_rn(s, __shfl_xor(s, 2));    // perfect tree over the 32 blocks
    s = __fadd_rn(s, __shfl_xor(s, 4));
    s = __fadd_rn(s, __shfl_xor(s, 8));
    s = __fadd_rn(s, __shfl_xor(s, 16));
    s = __fadd_rn(s, __shfl_xor(s, 32));
    if (L == 0) g_y[bc] = __fdiv_rn(s, 4096.0f);
}

// ---------------- Kernel 2: SE MLP (r12-verified bits) + PARTIAL rank ----------------
// 256 blocks x 512 threads; block (b = bid>>3, j = bid&7). Every block of batch b
// recomputes ss[512] bit-identically (w1 STAGED in LDS -- load-bearing, r20);
// block j accumulates ranks over candidate chunk [j*64, j*64+64) via atomicAdd.
__global__ __launch_bounds__(512) void se_rank_kernel(const float* __restrict__ w1,
                                                      const float* __restrict__ w2) {
    int b = blockIdx.x >> 3;
    int j = blockIdx.x & 7;
    int t = threadIdx.x;       // 0..511
    __shared__ float ys[C1];
    __shared__ float hs[CMID];
    __shared__ float ss[C1];
    __shared__ float w1s[CMID * W1PAD];   // 66 KB staged w1 (load-bearing)

    f32x4 w2r[8];
#pragma unroll
    for (int i = 0; i < 8; ++i)
        w2r[i] = ((const f32x4*)(w2 + t * CMID))[i];

#pragma unroll
    for (int i = 0; i < 8; ++i) {
        int u = i * 512 + t;               // f32x4 unit index in w1
        int row  = u >> 7;
        int col4 = u & 127;
        f32x4 v = ((const f32x4*)w1)[u];
        *(f32x4*)&w1s[row * W1PAD + col4 * 4] = v;
    }
    ys[t] = g_y[b * C1 + t];
    __syncthreads();

    // Layer 1: 32 rows x 4 independent SSE chains (numpy L0..L3), thread = (row,k)
    if (t < CMID * 4) {
        int row = t >> 2, k = t & 3;
        const float* wr = &w1s[row * W1PAD];
        float Lk = 0.f;
#pragma unroll
        for (int c = 0; c < C1; c += 8) {
            Lk = __fadd_rn(Lk, __fmul_rn(ys[c + k],     wr[c + k]));
            Lk = __fadd_rn(Lk, __fmul_rn(ys[c + 4 + k], wr[c + 4 + k]));
        }
        Lk = __fadd_rn(Lk, __shfl_xor(Lk, 1));   // (L0+L1),(L2+L3)
        Lk = __fadd_rn(Lk, __shfl_xor(Lk, 2));
        if (k == 0) hs[row] = Lk > 0.0f ? Lk : 0.0f;   // np.maximum(z, 0)
    }
    __syncthreads();

    // Layer 2: numpy SSE dot over CMID=32 (registers + LDS hs), then sigmoid
    {
        float L0 = 0.f, L1 = 0.f, L2 = 0.f, L3 = 0.f;
#pragma unroll
        for (int i = 0; i < 8; i += 2) {
            L0 = __fadd_rn(L0, __fmul_rn(hs[i * 4 + 0], w2r[i].x));
            L1 = __fadd_rn(L1, __fmul_rn(hs[i * 4 + 1], w2r[i].y));
            L2 = __fadd_rn(L2, __fmul_rn(hs[i * 4 + 2], w2r[i].z));
            L3 = __fadd_rn(L3, __fmul_rn(hs[i * 4 + 3], w2r[i].w));
            L0 = __fadd_rn(L0, __fmul_rn(hs[i * 4 + 4], w2r[i + 1].x));
            L1 = __fadd_rn(L1, __fmul_rn(hs[i * 4 + 5], w2r[i + 1].y));
            L2 = __fadd_rn(L2, __fmul_rn(hs[i * 4 + 6], w2r[i + 1].z));
            L3 = __fadd_rn(L3, __fmul_rn(hs[i * 4 + 7], w2r[i + 1].w));
        }
        float z = __fadd_rn(__fadd_rn(L0, L1), __fadd_rn(L2, L3));
        float e = (float)exp((double)(-z));      // correctly-rounded fp32 exp
        ss[t] = __fdiv_rn(1.0f, __fadd_rn(1.0f, e));
    }
    __syncthreads();

    // Partial stable-descending rank over candidate chunk [j*64, j*64+64):
    {
        float sc = ss[t];
        int c0 = j * 64;
        int rank = 0;
#pragma unroll 16
        for (int c = c0; c < c0 + 64; ++c) {
            float v = ss[c];
            rank += (int)((v > sc) || (v == sc && c < t));
        }
        atomicAdd(&g_rank[b * C1 + t], rank);   // int sum: order-independent
    }
}

// ---------------- Kernel 3: gather with in-block rank inversion (r18 verbatim) ------
// At BW floor (38.7us marginal, round-9 probe).
__global__ __launch_bounds__(512) void gather_kernel(const float* __restrict__ x,
                                                     float* __restrict__ out) {
    int bid = blockIdx.x;                      // plane 0..1023 (b*C2 + r)
    int b = bid >> 8;
    int r = bid & 255;
    int t = threadIdx.x;
    __shared__ int win;
    int rk = g_rank[b * C1 + t];
    if (rk == r) win = t;                      // exactly one match (ranks = perm)
    __syncthreads();
    int c = win;
    const f32x4* src = (const f32x4*)(x + ((size_t)(b * C1 + c)) * HW);
    f32x4* dst = (f32x4*)(out + (size_t)bid * HW);
    f32x4 v0 = src[t];
    f32x4 v1 = src[t + 512];
    __builtin_nontemporal_store(v0, &dst[t]);
    __builtin_nontemporal_store(v1, &dst[t + 512]);
}

extern "C" void kernel_launch(void* const* d_in, const int* in_sizes, int n_in,
                              void* d_out, int out_size, void* d_ws, size_t ws_size,
                              hipStream_t stream) {
    const float* x  = (const float*)d_in[0];
    const float* w1 = (const float*)d_in[1];
    const float* w2 = (const float*)d_in[2];
    float* out = (float*)d_out;

    pool_np_kernel<<<B * C1 / 4, 256, 0, stream>>>(x);
    se_rank_kernel<<<B * 8, 512, 0, stream>>>(w1, w2);
    gather_kernel<<<B * C2, 512, 0, stream>>>(x, out);
}